// Round 4
// baseline (40100.534 us; speedup 1.0000x reference)
//
#include <hip/hip_runtime.h>
#include <hip/hip_bf16.h>
#include <math.h>

using bf16 = __hip_bfloat16;

#define DI static __device__ __forceinline__

constexpr int Bc = 8, Nn = 4096, Gc = 128, Kc = 16, Vc = 64, Mc = 64;
constexpr int Dd = 384, NHh = 8, DHh = 48, FFf = 1536;

DI float b2f(bf16 h) { return __bfloat162float(h); }

// -------------------- dtype autodetect (inputs) --------------------
__global__ __launch_bounds__(256) void detect_kernel(const unsigned int* __restrict__ w, int* __restrict__ flag) {
    __shared__ int sh[256];
    int cnt = 0;
    for (int i = threadIdx.x; i < 16384; i += 256) {
        unsigned int lo = w[i] & 0xffffu;
        int e = (int)((lo >> 7) & 0xffu);
        if (e < 100 || e > 140) cnt++;
    }
    sh[threadIdx.x] = cnt;
    __syncthreads();
    for (int s = 128; s > 0; s >>= 1) {
        if (threadIdx.x < s) sh[threadIdx.x] += sh[threadIdx.x + s];
        __syncthreads();
    }
    if (threadIdx.x == 0) flag[0] = (sh[0] < 2048) ? 1 : 0;
}

DI float ldf(const void* p, size_t i, int isbf) {
    return isbf ? b2f(((const bf16*)p)[i]) : ((const float*)p)[i];
}

__global__ void cvtf_kernel(const void* __restrict__ src, float* __restrict__ dst, size_t n,
                            const int* __restrict__ flag) {
    size_t t = (size_t)blockIdx.x * 256 + threadIdx.x;
    if (t < n) dst[t] = ldf(src, t, flag[0]);
}

// fp32 copy to output
__global__ void copyout_kernel(const float* __restrict__ in, float* __restrict__ out, size_t n) {
    size_t t = (size_t)blockIdx.x * 256 + threadIdx.x;
    if (t < n) out[t] = in[t];
}

__global__ void zero_kernel(unsigned char* __restrict__ p, size_t n) {
    size_t t = (size_t)blockIdx.x * 256 + threadIdx.x;
    if (t < n) p[t] = 0;
}

__global__ void add_kernel(const float* __restrict__ a, const float* __restrict__ b,
                           float* __restrict__ o, size_t n) {
    size_t t = (size_t)blockIdx.x * 256 + threadIdx.x;
    if (t < n) o[t] = a[t] + b[t];
}

// -------------------- FPS --------------------
__global__ __launch_bounds__(256) void fps_kernel(const float* __restrict__ pos, float* __restrict__ cent) {
    __shared__ float px[Nn], py[Nn], pz[Nn];
    __shared__ float wv[4];
    __shared__ int wi[4];
    __shared__ int chosen;
    int b = blockIdx.x, tid = threadIdx.x;
    const float* p = pos + (size_t)b * Nn * 3;
    for (int i = tid; i < Nn; i += 256) { px[i] = p[3*i]; py[i] = p[3*i+1]; pz[i] = p[3*i+2]; }
    __syncthreads();
    float cx = px[0], cy = py[0], cz = pz[0];
    if (tid == 0) { float* c0 = cent + (size_t)b * Gc * 3; c0[0] = cx; c0[1] = cy; c0[2] = cz; }
    float mind[16];
#pragma unroll
    for (int j = 0; j < 16; j++) {
        int i = tid + 256 * j;
        float dx = px[i]-cx, dy = py[i]-cy, dz = pz[i]-cz;
        mind[j] = __fadd_rn(__fadd_rn(__fmul_rn(dx,dx), __fmul_rn(dy,dy)), __fmul_rn(dz,dz));
    }
    for (int s = 1; s < Gc; s++) {
        float bv = -1.f; int bi = 0;
#pragma unroll
        for (int j = 0; j < 16; j++) { int i = tid + 256*j; if (mind[j] > bv) { bv = mind[j]; bi = i; } }
        for (int o = 32; o > 0; o >>= 1) {
            float v2 = __shfl_down(bv, o, 64); int i2 = __shfl_down(bi, o, 64);
            if (v2 > bv || (v2 == bv && i2 < bi)) { bv = v2; bi = i2; }
        }
        if ((tid & 63) == 0) { wv[tid >> 6] = bv; wi[tid >> 6] = bi; }
        __syncthreads();
        if (tid == 0) {
            float fv = wv[0]; int fi = wi[0];
            for (int k = 1; k < 4; k++)
                if (wv[k] > fv || (wv[k] == fv && wi[k] < fi)) { fv = wv[k]; fi = wi[k]; }
            chosen = fi;
            float* cs = cent + ((size_t)b * Gc + s) * 3;
            cs[0] = px[fi]; cs[1] = py[fi]; cs[2] = pz[fi];
        }
        __syncthreads();
        int ci = chosen;
        float qx = px[ci], qy = py[ci], qz = pz[ci];
#pragma unroll
        for (int j = 0; j < 16; j++) {
            int i = tid + 256 * j;
            float dx = px[i]-qx, dy = py[i]-qy, dz = pz[i]-qz;
            float d = __fadd_rn(__fadd_rn(__fmul_rn(dx,dx), __fmul_rn(dy,dy)), __fmul_rn(dz,dz));
            if (d < mind[j]) mind[j] = d;
        }
    }
}

// -------------------- brute-force KNN (k=16), tie -> lower index --------------------
__global__ __launch_bounds__(64) void knn16_kernel(const float* __restrict__ q, const float* __restrict__ r,
                                                   int* __restrict__ nidx, int NQ, int NR) {
    __shared__ float dist[4096];
    int blk = blockIdx.x; int b = blk / NQ, qi = blk % NQ;
    int lane = threadIdx.x;
    const float* qp = q + ((size_t)b * NQ + qi) * 3;
    float qx = qp[0], qy = qp[1], qz = qp[2];
    float qq = __fadd_rn(__fadd_rn(__fmul_rn(qx,qx), __fmul_rn(qy,qy)), __fmul_rn(qz,qz));
    const float* rp = r + (size_t)b * NR * 3;
    for (int i = lane; i < NR; i += 64) {
        float rx = rp[3*i], ry = rp[3*i+1], rz = rp[3*i+2];
        float rr = __fadd_rn(__fadd_rn(__fmul_rn(rx,rx), __fmul_rn(ry,ry)), __fmul_rn(rz,rz));
        float dot = __fadd_rn(__fadd_rn(__fmul_rn(qx,rx), __fmul_rn(qy,ry)), __fmul_rn(qz,rz));
        dist[i] = __fadd_rn(__fadd_rn(qq, rr), -2.f * dot);
    }
    __syncthreads();
    int* out = nidx + ((size_t)b * NQ + qi) * Kc;
    for (int sel = 0; sel < Kc; ++sel) {
        float bv = INFINITY; int bi = 0;
        bool has = false;
        for (int i = lane; i < NR; i += 64) {
            float v = dist[i];
            if (!has || v < bv) { bv = v; bi = i; has = true; }
        }
        for (int o = 32; o > 0; o >>= 1) {
            float v2 = __shfl_xor(bv, o, 64); int i2 = __shfl_xor(bi, o, 64);
            if (v2 < bv || (v2 == bv && i2 < bi)) { bv = v2; bi = i2; }
        }
        if (lane == 0) { out[sel] = bi; dist[bi] = INFINITY; }
        __syncthreads();
    }
}

// -------------------- top-3 centers + interp weights --------------------
__global__ __launch_bounds__(64) void knn3_kernel(const float* __restrict__ pos, const float* __restrict__ cent,
                                                  int* __restrict__ idx3, float* __restrict__ w3) {
    int bn = blockIdx.x; int b = bn / Nn;
    int lane = threadIdx.x;
    const float* p = pos + (size_t)bn * 3;
    float px = p[0], py = p[1], pz = p[2];
    float pp = __fadd_rn(__fadd_rn(__fmul_rn(px,px), __fmul_rn(py,py)), __fmul_rn(pz,pz));
    float dv[2]; int di[2];
#pragma unroll
    for (int c = 0; c < 2; c++) {
        int g = lane + 64 * c;
        const float* cp = cent + ((size_t)b * Gc + g) * 3;
        float cx = cp[0], cy = cp[1], cz = cp[2];
        float cc = __fadd_rn(__fadd_rn(__fmul_rn(cx,cx), __fmul_rn(cy,cy)), __fmul_rn(cz,cz));
        float dot = __fadd_rn(__fadd_rn(__fmul_rn(px,cx), __fmul_rn(py,cy)), __fmul_rn(pz,cz));
        dv[c] = __fadd_rn(__fadd_rn(pp, cc), -2.f * dot);
        di[c] = g;
    }
    float od[3]; int oi[3];
#pragma unroll
    for (int r = 0; r < 3; r++) {
        float bv; int bi;
        if (dv[1] < dv[0]) { bv = dv[1]; bi = di[1]; } else { bv = dv[0]; bi = di[0]; }
        for (int o = 32; o > 0; o >>= 1) {
            float v2 = __shfl_xor(bv, o, 64); int i2 = __shfl_xor(bi, o, 64);
            if (v2 < bv || (v2 == bv && i2 < bi)) { bv = v2; bi = i2; }
        }
        od[r] = bv; oi[r] = bi;
        if (di[0] == bi) dv[0] = INFINITY;
        if (di[1] == bi) dv[1] = INFINITY;
    }
    if (lane == 0) {
        float w[3], s = 0.f;
        for (int r = 0; r < 3; r++) { w[r] = 1.f / (fmaxf(od[r], 0.f) + 1e-8f); s += w[r]; }
        for (int r = 0; r < 3; r++) { idx3[(size_t)bn*3 + r] = oi[r]; w3[(size_t)bn*3 + r] = w[r] / s; }
    }
}

// interp for rows [r0, r0+CH): out local (CH,387)
__global__ void interp_kernel(const float* __restrict__ feats, const float* __restrict__ pos,
                              const int* __restrict__ idx3, const float* __restrict__ w3,
                              float* __restrict__ x387, int r0, int CH) {
    size_t t = (size_t)blockIdx.x * 256 + threadIdx.x;
    size_t total = (size_t)CH * 387;
    if (t >= total) return;
    int c = (int)(t % 387); size_t i = t / 387;
    size_t r = (size_t)r0 + i; int b = (int)(r / Nn);
    float o;
    if (c < Dd) {
        o = 0.f;
        for (int k = 0; k < 3; k++)
            o += w3[r*3 + k] * feats[((size_t)b * Gc + idx3[r*3 + k]) * Dd + c];
    } else {
        o = pos[r*3 + (c - Dd)];
    }
    x387[t] = o;
}

// -------------------- tokenize helpers --------------------
__global__ void rel_kernel(const float* __restrict__ pos, const float* __restrict__ cent,
                           const int* __restrict__ nidx, float* __restrict__ rel) {
    int t = blockIdx.x * 256 + threadIdx.x;
    if (t >= Bc * Gc * Kc) return;
    int g = (t / Kc) % Gc; int b = t / (Kc * Gc);
    int pi = nidx[t];
    const float* p = pos + ((size_t)b * Nn + pi) * 3;
    const float* c = cent + ((size_t)b * Gc + g) * 3;
    float* o = rel + (size_t)t * 3;
    o[0] = p[0]-c[0]; o[1] = p[1]-c[1]; o[2] = p[2]-c[2];
}

__global__ void maxk_kernel(const float* __restrict__ in, float* __restrict__ out, int BG, int C) {
    int t = blockIdx.x * 256 + threadIdx.x;
    if (t >= BG * C) return;
    int c = t % C; int bg = t / C;
    const float* p = in + (size_t)bg * Kc * C + c;
    float m = -INFINITY;
    for (int k = 0; k < Kc; k++) m = fmaxf(m, p[(size_t)k * C]);
    out[t] = m;
}

__global__ void concat_gf_kernel(const float* __restrict__ g, const float* __restrict__ f,
                                 float* __restrict__ cat, int BG) {
    size_t t = (size_t)blockIdx.x * 256 + threadIdx.x;
    size_t total = (size_t)BG * Kc * 512;
    if (t >= total) return;
    int c = (int)(t % 512); size_t bgk = t / 512; size_t bg = bgk / Kc;
    cat[t] = (c < 256) ? g[bg * 256 + c] : f[bgk * 256 + (c - 256)];
}

// -------------------- gather / masks --------------------
__global__ void gather_rows_kernel(const float* __restrict__ in, const int* __restrict__ idx,
                                   float* __restrict__ out, int Ni, int C, int Sin) {
    size_t t = (size_t)blockIdx.x * 256 + threadIdx.x;
    size_t total = (size_t)Bc * Ni * C;
    if (t >= total) return;
    int c = (int)(t % C); size_t bi = t / C; int i = (int)(bi % Ni); int b = (int)(bi / Ni);
    int r = idx[(size_t)b * Ni + i];
    out[t] = in[((size_t)b * Sin + r) * C + c];
}

__global__ void scatter_mask_kernel(const int* __restrict__ nidx, unsigned char* __restrict__ mask,
                                    int Q, int S) {
    int t = blockIdx.x * 256 + threadIdx.x;
    if (t >= Bc * Q * Kc) return;
    int q = (t / Kc) % Q; int b = t / (Kc * Q);
    mask[((size_t)b * Q + q) * S + nidx[t]] = 1;
}

// -------------------- positional encoding (dst = base + pe) --------------------
__global__ void pe_kernel(float* __restrict__ dst, const float* __restrict__ base,
                          const float* __restrict__ xyz, size_t total) {
    size_t t = (size_t)blockIdx.x * 256 + threadIdx.x;
    if (t >= total) return;
    int d = (int)(t % Dd); size_t bs = t / Dd;
    int c = d >> 7;
    int i = d & 127;
    int j = i >> 1;
    float inv = expf(-0.1439115683121279f * (float)j);  // 10000^(-j/64)
    float val = xyz[bs * 3 + c] * inv;
    float pe = (i & 1) ? cosf(val) : sinf(val);
    dst[t] = (base ? base[t] : 0.f) + pe;
}

// -------------------- LayerNorm (no affine), row=384 --------------------
__global__ __launch_bounds__(256) void ln_kernel(const float* __restrict__ X, float* __restrict__ Y, int R) {
    int lane = threadIdx.x & 63;
    int row = blockIdx.x * 4 + (threadIdx.x >> 6);
    if (row >= R) return;
    const float* x = X + (size_t)row * Dd;
    float v[6]; float s = 0.f;
#pragma unroll
    for (int j = 0; j < 6; j++) { v[j] = x[lane + 64*j]; s += v[j]; }
#pragma unroll
    for (int o = 32; o > 0; o >>= 1) s += __shfl_xor(s, o, 64);
    float m = s * (1.f / Dd);
    float s2 = 0.f;
#pragma unroll
    for (int j = 0; j < 6; j++) { float d = v[j] - m; s2 += d * d; }
#pragma unroll
    for (int o = 32; o > 0; o >>= 1) s2 += __shfl_xor(s2, o, 64);
    float inv = rsqrtf(s2 * (1.f / Dd) + 1e-5f);
    float* y = Y + (size_t)row * Dd;
#pragma unroll
    for (int j = 0; j < 6; j++) y[lane + 64*j] = (v[j] - m) * inv;
}

// -------------------- generic fp32 GEMM; W/bias dtype via runtime flag --------------------
__global__ __launch_bounds__(256) void gemm_kernel(const float* __restrict__ A, const void* __restrict__ Wb,
                                                   size_t wOff, const void* __restrict__ Bb, size_t bOff,
                                                   const float* __restrict__ res, float* __restrict__ C,
                                                   int M, int Ncols, int Kk, int relu,
                                                   const int* __restrict__ flag) {
    __shared__ float As[16][65];
    __shared__ float Ws[16][65];
    const int isbf = flag[0];
    int tid = threadIdx.x;
    int row0 = blockIdx.y * 64, col0 = blockIdx.x * 64;
    int tx = tid & 15, ty = tid >> 4;
    float acc[4][4] = {{0.f}};
    for (int k0 = 0; k0 < Kk; k0 += 16) {
#pragma unroll
        for (int l = 0; l < 4; l++) {
            int i = tid + 256 * l;
            int m = i >> 4, kk = i & 15;
            int gm = row0 + m, gk = k0 + kk;
            As[kk][m] = (gm < M && gk < Kk) ? A[(size_t)gm * Kk + gk] : 0.f;
        }
#pragma unroll
        for (int l = 0; l < 4; l++) {
            int i = tid + 256 * l;
            int kk = i >> 6, n = i & 63;
            int gk = k0 + kk, gn = col0 + n;
            Ws[kk][n] = (gk < Kk && gn < Ncols) ? ldf(Wb, wOff + (size_t)gk * Ncols + gn, isbf) : 0.f;
        }
        __syncthreads();
#pragma unroll
        for (int kk = 0; kk < 16; kk++) {
            float a[4], w[4];
#pragma unroll
            for (int i = 0; i < 4; i++) a[i] = As[kk][ty*4 + i];
#pragma unroll
            for (int j = 0; j < 4; j++) w[j] = Ws[kk][tx*4 + j];
#pragma unroll
            for (int i = 0; i < 4; i++)
#pragma unroll
                for (int j = 0; j < 4; j++) acc[i][j] += a[i] * w[j];
        }
        __syncthreads();
    }
#pragma unroll
    for (int i = 0; i < 4; i++) {
        int gm = row0 + ty*4 + i;
        if (gm >= M) continue;
#pragma unroll
        for (int j = 0; j < 4; j++) {
            int gn = col0 + tx*4 + j;
            if (gn >= Ncols) continue;
            float v = acc[i][j];
            if (Bb) v += ldf(Bb, bOff + gn, isbf);
            if (relu) v = fmaxf(v, 0.f);
            if (res) v += res[(size_t)gm * Ncols + gn];
            C[(size_t)gm * Ncols + gn] = v;
        }
    }
}

// -------------------- fused attention: one wave per (bq,h,qi) --------------------
__global__ __launch_bounds__(64) void attn_kernel(const float* __restrict__ Q, const float* __restrict__ Kb,
                                                  const float* __restrict__ Vb,
                                                  const unsigned char* __restrict__ mask,
                                                  float* __restrict__ O, int Sq, int Sk, int b0) {
    int qi = blockIdx.x, h = blockIdx.y, bq = blockIdx.z;
    int bk = bq + b0;
    int lane = threadIdx.x;
    __shared__ float qv[DHh];
    __shared__ float pv[128];
    const size_t qrow = (size_t)bq * Sq + qi;
    if (lane < DHh) qv[lane] = Q[qrow * Dd + h * DHh + lane];
    __syncthreads();
    const float scale = 0.14433756729740643f;  // 1/sqrt(48)
    float lv[2] = {-INFINITY, -INFINITY};
#pragma unroll
    for (int c = 0; c < 2; c++) {
        int s = lane + 64 * c;
        if (s < Sk) {
            const float* kr = Kb + ((size_t)bk * Sk + s) * Dd + h * DHh;
            float d = 0.f;
#pragma unroll
            for (int t = 0; t < DHh; t++) d += qv[t] * kr[t];
            d *= scale;
            if (mask && !mask[qrow * Sk + s]) d = -1e9f;
            lv[c] = d;
        }
    }
    float mx = fmaxf(lv[0], lv[1]);
    for (int o = 32; o > 0; o >>= 1) mx = fmaxf(mx, __shfl_xor(mx, o, 64));
    float sum = 0.f;
#pragma unroll
    for (int c = 0; c < 2; c++) {
        int s = lane + 64 * c;
        if (s < Sk) { float e = expf(lv[c] - mx); pv[s] = e; sum += e; }
    }
    for (int o = 32; o > 0; o >>= 1) sum += __shfl_xor(sum, o, 64);
    float inv = 1.f / sum;
    __syncthreads();
    if (lane < DHh) {
        float acc = 0.f;
        const float* vb = Vb + (size_t)bk * Sk * Dd + h * DHh + lane;
        for (int s = 0; s < Sk; s++) acc += pv[s] * vb[(size_t)s * Dd];
        O[qrow * Dd + h * DHh + lane] = acc * inv;
    }
}

// -------------------- decoder q init --------------------
__global__ void dec_init_kernel(const float* __restrict__ mtok, const float* __restrict__ vout,
                                const float* __restrict__ cpe, const int* __restrict__ mski,
                                const int* __restrict__ visi, float* __restrict__ x) {
    size_t t = (size_t)blockIdx.x * 256 + threadIdx.x;
    size_t total = (size_t)Bc * Gc * Dd;
    if (t >= total) return;
    int d = (int)(t % Dd); size_t bi = t / Dd; int i = (int)(bi % Gc); int b = (int)(bi / Gc);
    float base; int ci;
    if (i < Mc) { base = mtok[d]; ci = mski[b * Mc + i]; }
    else        { base = vout[((size_t)b * Vc + (i - Mc)) * Dd + d]; ci = visi[b * Vc + (i - Mc)]; }
    x[t] = base + cpe[((size_t)b * Gc + ci) * Dd + d];
}

// -------------------- smooth-L1 partial reduce --------------------
__global__ __launch_bounds__(256) void sl1_kernel(const float* __restrict__ tgt, const float* __restrict__ dec,
                                                  float* __restrict__ acc, int slot) {
    __shared__ float sh[256];
    size_t t = (size_t)blockIdx.x * 256 + threadIdx.x;
    const size_t total = (size_t)Bc * Mc * Dd;
    float v = 0.f;
    if (t < total) {
        int d = (int)(t % Dd); size_t rem = t / Dd; int i = (int)(rem % Mc); int b = (int)(rem / Mc);
        float p = dec[((size_t)b * Gc + i) * Dd + d];
        float a = fabsf(p - tgt[t]);
        v = (a < 2.f) ? 0.25f * a * a : (a - 1.f);
    }
    sh[threadIdx.x] = v;
    __syncthreads();
    for (int s = 128; s > 0; s >>= 1) {
        if (threadIdx.x < s) sh[threadIdx.x] += sh[threadIdx.x + s];
        __syncthreads();
    }
    if (threadIdx.x == 0) atomicAdd(&acc[slot], sh[0]);
}

__global__ void mae_finalize_kernel(const float* __restrict__ acc, float* __restrict__ out) {
    const float inv = 1.f / (float)(Bc * Mc * Dd);
    *out = 0.5f * (acc[0] * inv) + 0.5f * (acc[1] * inv);
}

// ==================== host orchestration ====================
extern "C" void kernel_launch(void* const* d_in, const int* in_sizes, int n_in,
                              void* d_out, int out_size, void* d_ws, size_t ws_size,
                              hipStream_t stream) {
    (void)in_sizes; (void)n_in; (void)out_size;
    const void* pos_src = d_in[0];
    const void* pos_tgt = d_in[1];
    const int* vis_s = (const int*)d_in[2];
    const int* msk_s = (const int*)d_in[3];
    const int* vis_t = (const int*)d_in[4];
    const int* msk_t = (const int*)d_in[5];
    const void *tw1 = d_in[6], *tb1 = d_in[7], *tw2 = d_in[8], *tb2 = d_in[9];
    const void *tw3 = d_in[10], *tb3 = d_in[11], *tw4 = d_in[12], *tb4 = d_in[13];
    const void *mtok = d_in[14];
    const void *cxw = d_in[15], *cff1 = d_in[16], *cff2 = d_in[17];
    const void *esa = d_in[18], *eca = d_in[19], *eff1 = d_in[20], *eff2 = d_in[21];
    const void *dca = d_in[22], *dff1 = d_in[23], *dff2 = d_in[24];
    const void *uw1 = d_in[25], *ub1 = d_in[26], *uw2 = d_in[27], *ub2 = d_in[28];
    float* out = (float*)d_out;                      // OUTPUT IS FLOAT32
    char* ws = (char*)d_ws;

    const size_t DD = (size_t)Dd * Dd;
    const size_t DF = (size_t)Dd * FFf;

    // ---- persistent workspace layout ----
    size_t o = 0;
    auto alloc = [&](size_t bytes) -> size_t { size_t r = o; o += (bytes + 255) & ~(size_t)255; return r; };
    const size_t flagO = alloc(256);
    const size_t mtokO = alloc(Dd * 4);
    const size_t posf_s = alloc((size_t)Bc*Nn*3*4), posf_t = alloc((size_t)Bc*Nn*3*4);
    const size_t cent_s = alloc((size_t)Bc*Gc*3*4), cent_t = alloc((size_t)Bc*Gc*3*4);
    const size_t cpe_s = alloc((size_t)Bc*Gc*Dd*4), cpe_t = alloc((size_t)Bc*Gc*Dd*4);
    const size_t tok_s = alloc((size_t)Bc*Gc*Dd*4), tok_t = alloc((size_t)Bc*Gc*Dd*4);
    const size_t vtok_s = alloc((size_t)Bc*Vc*Dd*4), vtok_t = alloc((size_t)Bc*Vc*Dd*4);
    const size_t lnS = alloc((size_t)Bc*Gc*Dd*4), lnT = alloc((size_t)Bc*Gc*Dd*4);
    const size_t qb = alloc((size_t)Bc*Gc*Dd*4), kb = alloc((size_t)Bc*Gc*Dd*4);
    const size_t vb = alloc((size_t)Bc*Gc*Dd*4), cx = alloc((size_t)Bc*Gc*Dd*4);
    const size_t decx_s = alloc((size_t)Bc*Gc*Dd*4), decx_t = alloc((size_t)Bc*Gc*Dd*4);
    const size_t memb = alloc((size_t)Bc*Gc*Dd*4), lnm = alloc((size_t)Bc*Gc*Dd*4);
    const size_t kl0 = alloc((size_t)Bc*Gc*Dd*4), vl0 = alloc((size_t)Bc*Gc*Dd*4);
    const size_t kl1 = alloc((size_t)Bc*Gc*Dd*4), vl1 = alloc((size_t)Bc*Gc*Dd*4);
    const size_t relb = alloc((size_t)Bc*Gc*Kc*3*4);
    const size_t tbs = alloc((size_t)Bc*Mc*Dd*4), tbt = alloc((size_t)Bc*Mc*Dd*4);
    const size_t mfull_s = alloc((size_t)Bc*Gc*Gc), mfull_t = alloc((size_t)Bc*Gc*Gc);
    const size_t mvis_s = alloc((size_t)Bc*Vc*Vc), mvis_t = alloc((size_t)Bc*Vc*Vc);
    const size_t nidxb = alloc((size_t)Bc*Gc*Kc*4);
    const size_t idx3b = alloc((size_t)Bc*Nn*3*4), w3b = alloc((size_t)Bc*Nn*3*4);
    const size_t vis3_s = alloc((size_t)Bc*Vc*3*4), vis3_t = alloc((size_t)Bc*Vc*3*4);
    const size_t accb = alloc(64);

    // ---- chunk size selection based on ws_size ----
    int CH = 256;
    {
        const int cands[5] = {4096, 2048, 1024, 512, 256};
        for (int ci = 0; ci < 5; ci++) {
            size_t need = o + (size_t)cands[ci] * 3715 * 4 + 8 * 256;
            if (need <= ws_size) { CH = cands[ci]; break; }
        }
    }
    const size_t AcbO = alloc((size_t)CH*387*4);
    const size_t XcO  = alloc((size_t)CH*384*4);
    const size_t LcO  = alloc((size_t)CH*384*4);
    const size_t T1O  = alloc((size_t)CH*512*4);
    const size_t T2O  = alloc((size_t)CH*512*4);
    const size_t HhO  = alloc((size_t)CH*FFf*4);

    auto F = [&](size_t off) -> float* { return (float*)(ws + off); };
    auto I = [&](size_t off) -> int* { return (int*)(ws + off); };
    auto U = [&](size_t off) -> unsigned char* { return (unsigned char*)(ws + off); };
    auto ew = [](size_t n) -> dim3 { return dim3((unsigned)((n + 255) / 256)); };
    const int* flag = I(flagO);

    auto gemm = [&](const float* A, const void* W, size_t wOff, const void* bias, size_t bOff,
                    const float* res, float* C, int M, int Ncol, int Kk, int relu) {
        dim3 g((Ncol + 63) / 64, (M + 63) / 64);
        gemm_kernel<<<g, 256, 0, stream>>>(A, W, wOff, bias, bOff, res, C, M, Ncol, Kk, relu, flag);
    };
    auto ln = [&](const float* X, float* Y, int R) {
        ln_kernel<<<dim3((R + 3) / 4), 256, 0, stream>>>(X, Y, R);
    };
    auto attn = [&](const float* Qp, const float* Kp, const float* Vp, const unsigned char* mask,
                    float* Op, int Sq, int Sk, int nb, int b0) {
        attn_kernel<<<dim3(Sq, NHh, nb), 64, 0, stream>>>(Qp, Kp, Vp, mask, Op, Sq, Sk, b0);
    };
    float *qbuf = F(qb), *kbuf = F(kb), *vbuf = F(vb), *ctx = F(cx);
    auto attn_block = [&](float* x, const float* qln, const float* kln, const void* w, size_t wo,
                          const unsigned char* mask, int S) {
        gemm(qln, w, wo,        nullptr, 0, nullptr, qbuf, Bc*S, Dd, Dd, 0);
        gemm(kln, w, wo + DD,   nullptr, 0, nullptr, kbuf, Bc*S, Dd, Dd, 0);
        gemm(kln, w, wo + 2*DD, nullptr, 0, nullptr, vbuf, Bc*S, Dd, Dd, 0);
        attn(qbuf, kbuf, vbuf, mask, ctx, S, S, Bc, 0);
        gemm(ctx, w, wo + 3*DD, nullptr, 0, x, x, Bc*S, Dd, Dd, 0);
    };
    auto ffn = [&](float* x, const void* w1, size_t w1o, const void* w2, size_t w2o, int R) {
        ln(x, F(lnS), R);
        for (int r0 = 0; r0 < R; r0 += CH) {
            int rc = (R - r0 < CH) ? (R - r0) : CH;
            gemm(F(lnS) + (size_t)r0*Dd, w1, w1o, nullptr, 0, nullptr, F(HhO), rc, FFf, Dd, 1);
            gemm(F(HhO), w2, w2o, nullptr, 0, x + (size_t)r0*Dd, x + (size_t)r0*Dd, rc, Dd, FFf, 0);
        }
    };
    auto cross_enc = [&](float* xs, float* xt, const unsigned char* ms, const unsigned char* mt, int S) {
        ln(xs, F(lnS), Bc*S); attn_block(xs, F(lnS), F(lnS), cxw, 0, ms, S);
        ln(xt, F(lnT), Bc*S); attn_block(xt, F(lnT), F(lnT), cxw, 0, mt, S);
        ln(xs, F(lnS), Bc*S); ln(xt, F(lnT), Bc*S);
        attn_block(xs, F(lnS), F(lnT), cxw, 4*DD, nullptr, S);
        attn_block(xt, F(lnT), F(lnS), cxw, 4*DD, nullptr, S);
        ffn(xs, cff1, 0, cff2, 0, Bc*S);
        ffn(xt, cff1, 0, cff2, 0, Bc*S);
    };
    auto decoder4 = [&](float* x, const float* memin, const float* cpem) {
        add_kernel<<<ew((size_t)Bc*Gc*Dd), 256, 0, stream>>>(memin, cpem, F(memb), (size_t)Bc*Gc*Dd);
        ln(F(memb), F(lnm), Bc*Gc);
        for (int l = 0; l < 4; l++) {
            ln(x, F(lnT), Bc*Gc);
            attn_block(x, F(lnT), F(lnT), esa, (size_t)l*4*DD, nullptr, Gc);
            ln(x, F(lnT), Bc*Gc);
            attn_block(x, F(lnT), F(lnm), eca, (size_t)l*4*DD, nullptr, Gc);
            ffn(x, eff1, (size_t)l*DF, eff2, (size_t)l*DF, Bc*Gc);
        }
    };
    auto tokenize = [&](const float* posf, float* cent, float* tok) {
        fps_kernel<<<dim3(Bc), 256, 0, stream>>>(posf, cent);
        knn16_kernel<<<dim3(Bc*Gc), 64, 0, stream>>>(cent, posf, I(nidxb), Gc, Nn);
        rel_kernel<<<ew((size_t)Bc*Gc*Kc), 256, 0, stream>>>(posf, cent, I(nidxb), F(relb));
        const int GC = CH / Kc;             // groups per chunk
        float* Hh0 = F(HhO);                      // cat (CH x 512)
        float* Hh1 = F(HhO) + (size_t)CH * 512;   // hb  (CH x 512)
        for (int g0 = 0; g0 < Bc*Gc; g0 += GC) {
            const int RC = GC * Kc;
            gemm(F(relb) + (size_t)g0*Kc*3, tw1, 0, tb1, 0, nullptr, F(T1O), RC, 128, 3, 1);
            gemm(F(T1O), tw2, 0, tb2, 0, nullptr, F(T2O), RC, 256, 128, 0);
            maxk_kernel<<<ew((size_t)GC*256), 256, 0, stream>>>(F(T2O), F(XcO), GC, 256);
            concat_gf_kernel<<<ew((size_t)RC*512), 256, 0, stream>>>(F(XcO), F(T2O), Hh0, GC);
            gemm(Hh0, tw3, 0, tb3, 0, nullptr, Hh1, RC, 512, 512, 1);
            gemm(Hh1, tw4, 0, tb4, 0, nullptr, F(XcO), RC, Dd, 512, 0);
            maxk_kernel<<<ew((size_t)GC*Dd), 256, 0, stream>>>(F(XcO), tok + (size_t)g0*Dd, GC, Dd);
        }
    };
    auto dense_side = [&](const float* posf, const float* cent, const float* feats,
                          const float* cpe_side, float* outp) {
        knn3_kernel<<<dim3(Bc*Nn), 64, 0, stream>>>(posf, cent, I(idx3b), F(w3b));
        add_kernel<<<ew((size_t)Bc*Gc*Dd), 256, 0, stream>>>(feats, cpe_side, F(memb), (size_t)Bc*Gc*Dd);
        ln(F(memb), F(lnm), Bc*Gc);
        gemm(F(lnm), dca, 0*4*DD + DD,   nullptr, 0, nullptr, F(kl0), Bc*Gc, Dd, Dd, 0);
        gemm(F(lnm), dca, 0*4*DD + 2*DD, nullptr, 0, nullptr, F(vl0), Bc*Gc, Dd, Dd, 0);
        gemm(F(lnm), dca, 1*4*DD + DD,   nullptr, 0, nullptr, F(kl1), Bc*Gc, Dd, Dd, 0);
        gemm(F(lnm), dca, 1*4*DD + 2*DD, nullptr, 0, nullptr, F(vl1), Bc*Gc, Dd, Dd, 0);
        const size_t kvo[2][2] = {{kl0, vl0}, {kl1, vl1}};
        for (int b = 0; b < Bc; b++) {
            for (int c0 = 0; c0 < Nn; c0 += CH) {
                const int r0 = b * Nn + c0;
                interp_kernel<<<ew((size_t)CH*387), 256, 0, stream>>>(feats, posf, I(idx3b), F(w3b), F(AcbO), r0, CH);
                gemm(F(AcbO), uw1, 0, ub1, 0, nullptr, F(XcO), CH, Dd, 387, 1);
                gemm(F(XcO), uw2, 0, ub2, 0, nullptr, F(LcO), CH, Dd, Dd, 1);
                pe_kernel<<<ew((size_t)CH*Dd), 256, 0, stream>>>(F(XcO), F(LcO), posf + (size_t)r0*3, (size_t)CH*Dd);
                for (int l = 0; l < 2; l++) {
                    ln(F(XcO), F(LcO), CH);
                    gemm(F(LcO), dca, (size_t)l*4*DD, nullptr, 0, nullptr, F(T1O), CH, Dd, Dd, 0);
                    attn(F(T1O), F(kvo[l][0]), F(kvo[l][1]), nullptr, F(T2O), CH, Gc, 1, b);
                    gemm(F(T2O), dca, (size_t)l*4*DD + 3*DD, nullptr, 0, F(XcO), F(XcO), CH, Dd, Dd, 0);
                    ln(F(XcO), F(LcO), CH);
                    gemm(F(LcO), dff1, (size_t)l*DF, nullptr, 0, nullptr, F(HhO), CH, FFf, Dd, 1);
                    gemm(F(HhO), dff2, (size_t)l*DF, nullptr, 0, F(XcO), F(XcO), CH, Dd, FFf, 0);
                }
                copyout_kernel<<<ew((size_t)CH*Dd), 256, 0, stream>>>(F(XcO), outp + (size_t)r0*Dd, (size_t)CH*Dd);
            }
        }
    };

    // ---- pipeline ----
    detect_kernel<<<dim3(1), 256, 0, stream>>>((const unsigned int*)pos_src, I(flagO));
    cvtf_kernel<<<ew((size_t)Bc*Nn*3), 256, 0, stream>>>(pos_src, F(posf_s), (size_t)Bc*Nn*3, flag);
    cvtf_kernel<<<ew((size_t)Bc*Nn*3), 256, 0, stream>>>(pos_tgt, F(posf_t), (size_t)Bc*Nn*3, flag);
    cvtf_kernel<<<dim3(2), 256, 0, stream>>>(mtok, F(mtokO), (size_t)Dd, flag);

    tokenize(F(posf_s), F(cent_s), F(tok_s));
    tokenize(F(posf_t), F(cent_t), F(tok_t));

    pe_kernel<<<ew((size_t)Bc*Gc*Dd), 256, 0, stream>>>(F(cpe_s), nullptr, F(cent_s), (size_t)Bc*Gc*Dd);
    pe_kernel<<<ew((size_t)Bc*Gc*Dd), 256, 0, stream>>>(F(cpe_t), nullptr, F(cent_t), (size_t)Bc*Gc*Dd);

    gather_rows_kernel<<<ew((size_t)Bc*Vc*Dd), 256, 0, stream>>>(F(tok_s), vis_s, F(vtok_s), Vc, Dd, Gc);
    gather_rows_kernel<<<ew((size_t)Bc*Vc*Dd), 256, 0, stream>>>(F(tok_t), vis_t, F(vtok_t), Vc, Dd, Gc);
    gather_rows_kernel<<<ew((size_t)Bc*Vc*3), 256, 0, stream>>>(F(cent_s), vis_s, F(vis3_s), Vc, 3, Gc);
    gather_rows_kernel<<<ew((size_t)Bc*Vc*3), 256, 0, stream>>>(F(cent_t), vis_t, F(vis3_t), Vc, 3, Gc);

    zero_kernel<<<ew((size_t)Bc*Gc*Gc), 256, 0, stream>>>(U(mfull_s), (size_t)Bc*Gc*Gc);
    knn16_kernel<<<dim3(Bc*Gc), 64, 0, stream>>>(F(cent_s), F(cent_s), I(nidxb), Gc, Gc);
    scatter_mask_kernel<<<ew((size_t)Bc*Gc*Kc), 256, 0, stream>>>(I(nidxb), U(mfull_s), Gc, Gc);
    zero_kernel<<<ew((size_t)Bc*Gc*Gc), 256, 0, stream>>>(U(mfull_t), (size_t)Bc*Gc*Gc);
    knn16_kernel<<<dim3(Bc*Gc), 64, 0, stream>>>(F(cent_t), F(cent_t), I(nidxb), Gc, Gc);
    scatter_mask_kernel<<<ew((size_t)Bc*Gc*Kc), 256, 0, stream>>>(I(nidxb), U(mfull_t), Gc, Gc);
    zero_kernel<<<ew((size_t)Bc*Vc*Vc), 256, 0, stream>>>(U(mvis_s), (size_t)Bc*Vc*Vc);
    knn16_kernel<<<dim3(Bc*Vc), 64, 0, stream>>>(F(vis3_s), F(vis3_s), I(nidxb), Vc, Vc);
    scatter_mask_kernel<<<ew((size_t)Bc*Vc*Kc), 256, 0, stream>>>(I(nidxb), U(mvis_s), Vc, Vc);
    zero_kernel<<<ew((size_t)Bc*Vc*Vc), 256, 0, stream>>>(U(mvis_t), (size_t)Bc*Vc*Vc);
    knn16_kernel<<<dim3(Bc*Vc), 64, 0, stream>>>(F(vis3_t), F(vis3_t), I(nidxb), Vc, Vc);
    scatter_mask_kernel<<<ew((size_t)Bc*Vc*Kc), 256, 0, stream>>>(I(nidxb), U(mvis_t), Vc, Vc);

    cross_enc(F(vtok_s), F(vtok_t), U(mvis_s), U(mvis_t), Vc);
    cross_enc(F(tok_s), F(tok_t), U(mfull_s), U(mfull_t), Gc);

    dec_init_kernel<<<ew((size_t)Bc*Gc*Dd), 256, 0, stream>>>(F(mtokO), F(vtok_s), F(cpe_s), msk_s, vis_s, F(decx_s));
    dec_init_kernel<<<ew((size_t)Bc*Gc*Dd), 256, 0, stream>>>(F(mtokO), F(vtok_t), F(cpe_t), msk_t, vis_t, F(decx_t));
    decoder4(F(decx_s), F(tok_t), F(cpe_t));
    decoder4(F(decx_t), F(tok_s), F(cpe_s));

    zero_kernel<<<dim3(1), 256, 0, stream>>>(U(accb), 64);
    gather_rows_kernel<<<ew((size_t)Bc*Mc*Dd), 256, 0, stream>>>(F(tok_s), msk_s, F(tbs), Mc, Dd, Gc);
    gather_rows_kernel<<<ew((size_t)Bc*Mc*Dd), 256, 0, stream>>>(F(tok_t), msk_t, F(tbt), Mc, Dd, Gc);
    sl1_kernel<<<ew((size_t)Bc*Mc*Dd), 256, 0, stream>>>(F(tbs), F(decx_s), F(accb), 0);
    sl1_kernel<<<ew((size_t)Bc*Mc*Dd), 256, 0, stream>>>(F(tbt), F(decx_t), F(accb), 1);

    dense_side(F(posf_s), F(cent_s), F(tok_s), F(cpe_s), out);
    dense_side(F(posf_t), F(cent_t), F(tok_t), F(cpe_t), out + (size_t)Bc*Nn*Dd);

    mae_finalize_kernel<<<dim3(1), 1, 0, stream>>>(F(accb), out + (size_t)2*Bc*Nn*Dd);
}

// Round 5
// 29051.740 us; speedup vs baseline: 1.3803x; 1.3803x over previous
//
#include <hip/hip_runtime.h>
#include <hip/hip_bf16.h>
#include <math.h>

using bf16 = __hip_bfloat16;

#define DI static __device__ __forceinline__

constexpr int Bc = 8, Nn = 4096, Gc = 128, Kc = 16, Vc = 64, Mc = 64;
constexpr int Dd = 384, NHh = 8, DHh = 48, FFf = 1536;

typedef __bf16 bf8v __attribute__((ext_vector_type(8)));
typedef float f4v __attribute__((ext_vector_type(4)));

DI float b2f(bf16 h) { return __bfloat162float(h); }
DI __bf16 f2b(float f) { return (__bf16)f; }

// -------------------- dtype autodetect (inputs) --------------------
__global__ __launch_bounds__(256) void detect_kernel(const unsigned int* __restrict__ w, int* __restrict__ flag) {
    __shared__ int sh[256];
    int cnt = 0;
    for (int i = threadIdx.x; i < 16384; i += 256) {
        unsigned int lo = w[i] & 0xffffu;
        int e = (int)((lo >> 7) & 0xffu);
        if (e < 100 || e > 140) cnt++;
    }
    sh[threadIdx.x] = cnt;
    __syncthreads();
    for (int s = 128; s > 0; s >>= 1) {
        if (threadIdx.x < s) sh[threadIdx.x] += sh[threadIdx.x + s];
        __syncthreads();
    }
    if (threadIdx.x == 0) flag[0] = (sh[0] < 2048) ? 1 : 0;
}

DI float ldf(const void* p, size_t i, int isbf) {
    return isbf ? b2f(((const bf16*)p)[i]) : ((const float*)p)[i];
}

__global__ void cvtf_kernel(const void* __restrict__ src, float* __restrict__ dst, size_t n,
                            const int* __restrict__ flag) {
    size_t t = (size_t)blockIdx.x * 256 + threadIdx.x;
    if (t < n) dst[t] = ldf(src, t, flag[0]);
}

__global__ void copyout_kernel(const float* __restrict__ in, float* __restrict__ out, size_t n) {
    size_t t = (size_t)blockIdx.x * 256 + threadIdx.x;
    if (t < n) out[t] = in[t];
}

__global__ void zero_kernel(unsigned char* __restrict__ p, size_t n) {
    size_t t = (size_t)blockIdx.x * 256 + threadIdx.x;
    if (t < n) p[t] = 0;
}

__global__ void add_kernel(const float* __restrict__ a, const float* __restrict__ b,
                           float* __restrict__ o, size_t n) {
    size_t t = (size_t)blockIdx.x * 256 + threadIdx.x;
    if (t < n) o[t] = a[t] + b[t];
}

// -------------------- FPS --------------------
__global__ __launch_bounds__(256) void fps_kernel(const float* __restrict__ pos, float* __restrict__ cent) {
    __shared__ float px[Nn], py[Nn], pz[Nn];
    __shared__ float wv[4];
    __shared__ int wi[4];
    __shared__ int chosen;
    int b = blockIdx.x, tid = threadIdx.x;
    const float* p = pos + (size_t)b * Nn * 3;
    for (int i = tid; i < Nn; i += 256) { px[i] = p[3*i]; py[i] = p[3*i+1]; pz[i] = p[3*i+2]; }
    __syncthreads();
    float cx = px[0], cy = py[0], cz = pz[0];
    if (tid == 0) { float* c0 = cent + (size_t)b * Gc * 3; c0[0] = cx; c0[1] = cy; c0[2] = cz; }
    float mind[16];
#pragma unroll
    for (int j = 0; j < 16; j++) {
        int i = tid + 256 * j;
        float dx = px[i]-cx, dy = py[i]-cy, dz = pz[i]-cz;
        mind[j] = __fadd_rn(__fadd_rn(__fmul_rn(dx,dx), __fmul_rn(dy,dy)), __fmul_rn(dz,dz));
    }
    for (int s = 1; s < Gc; s++) {
        float bv = -1.f; int bi = 0;
#pragma unroll
        for (int j = 0; j < 16; j++) { int i = tid + 256*j; if (mind[j] > bv) { bv = mind[j]; bi = i; } }
        for (int o = 32; o > 0; o >>= 1) {
            float v2 = __shfl_down(bv, o, 64); int i2 = __shfl_down(bi, o, 64);
            if (v2 > bv || (v2 == bv && i2 < bi)) { bv = v2; bi = i2; }
        }
        if ((tid & 63) == 0) { wv[tid >> 6] = bv; wi[tid >> 6] = bi; }
        __syncthreads();
        if (tid == 0) {
            float fv = wv[0]; int fi = wi[0];
            for (int k = 1; k < 4; k++)
                if (wv[k] > fv || (wv[k] == fv && wi[k] < fi)) { fv = wv[k]; fi = wi[k]; }
            chosen = fi;
            float* cs = cent + ((size_t)b * Gc + s) * 3;
            cs[0] = px[fi]; cs[1] = py[fi]; cs[2] = pz[fi];
        }
        __syncthreads();
        int ci = chosen;
        float qx = px[ci], qy = py[ci], qz = pz[ci];
#pragma unroll
        for (int j = 0; j < 16; j++) {
            int i = tid + 256 * j;
            float dx = px[i]-qx, dy = py[i]-qy, dz = pz[i]-qz;
            float d = __fadd_rn(__fadd_rn(__fmul_rn(dx,dx), __fmul_rn(dy,dy)), __fmul_rn(dz,dz));
            if (d < mind[j]) mind[j] = d;
        }
    }
}

// -------------------- brute-force KNN (k=16), tie -> lower index --------------------
__global__ __launch_bounds__(64) void knn16_kernel(const float* __restrict__ q, const float* __restrict__ r,
                                                   int* __restrict__ nidx, int NQ, int NR) {
    __shared__ float dist[4096];
    int blk = blockIdx.x; int b = blk / NQ, qi = blk % NQ;
    int lane = threadIdx.x;
    const float* qp = q + ((size_t)b * NQ + qi) * 3;
    float qx = qp[0], qy = qp[1], qz = qp[2];
    float qq = __fadd_rn(__fadd_rn(__fmul_rn(qx,qx), __fmul_rn(qy,qy)), __fmul_rn(qz,qz));
    const float* rp = r + (size_t)b * NR * 3;
    for (int i = lane; i < NR; i += 64) {
        float rx = rp[3*i], ry = rp[3*i+1], rz = rp[3*i+2];
        float rr = __fadd_rn(__fadd_rn(__fmul_rn(rx,rx), __fmul_rn(ry,ry)), __fmul_rn(rz,rz));
        float dot = __fadd_rn(__fadd_rn(__fmul_rn(qx,rx), __fmul_rn(qy,ry)), __fmul_rn(qz,rz));
        dist[i] = __fadd_rn(__fadd_rn(qq, rr), -2.f * dot);
    }
    __syncthreads();
    int* out = nidx + ((size_t)b * NQ + qi) * Kc;
    for (int sel = 0; sel < Kc; ++sel) {
        float bv = INFINITY; int bi = 0;
        bool has = false;
        for (int i = lane; i < NR; i += 64) {
            float v = dist[i];
            if (!has || v < bv) { bv = v; bi = i; has = true; }
        }
        for (int o = 32; o > 0; o >>= 1) {
            float v2 = __shfl_xor(bv, o, 64); int i2 = __shfl_xor(bi, o, 64);
            if (v2 < bv || (v2 == bv && i2 < bi)) { bv = v2; bi = i2; }
        }
        if (lane == 0) { out[sel] = bi; dist[bi] = INFINITY; }
        __syncthreads();
    }
}

// -------------------- top-3 centers + interp weights --------------------
__global__ __launch_bounds__(64) void knn3_kernel(const float* __restrict__ pos, const float* __restrict__ cent,
                                                  int* __restrict__ idx3, float* __restrict__ w3) {
    int bn = blockIdx.x; int b = bn / Nn;
    int lane = threadIdx.x;
    const float* p = pos + (size_t)bn * 3;
    float px = p[0], py = p[1], pz = p[2];
    float pp = __fadd_rn(__fadd_rn(__fmul_rn(px,px), __fmul_rn(py,py)), __fmul_rn(pz,pz));
    float dv[2]; int di[2];
#pragma unroll
    for (int c = 0; c < 2; c++) {
        int g = lane + 64 * c;
        const float* cp = cent + ((size_t)b * Gc + g) * 3;
        float cx = cp[0], cy = cp[1], cz = cp[2];
        float cc = __fadd_rn(__fadd_rn(__fmul_rn(cx,cx), __fmul_rn(cy,cy)), __fmul_rn(cz,cz));
        float dot = __fadd_rn(__fadd_rn(__fmul_rn(px,cx), __fmul_rn(py,cy)), __fmul_rn(pz,cz));
        dv[c] = __fadd_rn(__fadd_rn(pp, cc), -2.f * dot);
        di[c] = g;
    }
    float od[3]; int oi[3];
#pragma unroll
    for (int r = 0; r < 3; r++) {
        float bv; int bi;
        if (dv[1] < dv[0]) { bv = dv[1]; bi = di[1]; } else { bv = dv[0]; bi = di[0]; }
        for (int o = 32; o > 0; o >>= 1) {
            float v2 = __shfl_xor(bv, o, 64); int i2 = __shfl_xor(bi, o, 64);
            if (v2 < bv || (v2 == bv && i2 < bi)) { bv = v2; bi = i2; }
        }
        od[r] = bv; oi[r] = bi;
        if (di[0] == bi) dv[0] = INFINITY;
        if (di[1] == bi) dv[1] = INFINITY;
    }
    if (lane == 0) {
        float w[3], s = 0.f;
        for (int r = 0; r < 3; r++) { w[r] = 1.f / (fmaxf(od[r], 0.f) + 1e-8f); s += w[r]; }
        for (int r = 0; r < 3; r++) { idx3[(size_t)bn*3 + r] = oi[r]; w3[(size_t)bn*3 + r] = w[r] / s; }
    }
}

// interp for rows [r0, r0+CH): out local (CH,387)
__global__ void interp_kernel(const float* __restrict__ feats, const float* __restrict__ pos,
                              const int* __restrict__ idx3, const float* __restrict__ w3,
                              float* __restrict__ x387, int r0, int CH) {
    size_t t = (size_t)blockIdx.x * 256 + threadIdx.x;
    size_t total = (size_t)CH * 387;
    if (t >= total) return;
    int c = (int)(t % 387); size_t i = t / 387;
    size_t r = (size_t)r0 + i; int b = (int)(r / Nn);
    float o;
    if (c < Dd) {
        o = 0.f;
        for (int k = 0; k < 3; k++)
            o += w3[r*3 + k] * feats[((size_t)b * Gc + idx3[r*3 + k]) * Dd + c];
    } else {
        o = pos[r*3 + (c - Dd)];
    }
    x387[t] = o;
}

// -------------------- tokenize helpers --------------------
__global__ void rel_kernel(const float* __restrict__ pos, const float* __restrict__ cent,
                           const int* __restrict__ nidx, float* __restrict__ rel) {
    int t = blockIdx.x * 256 + threadIdx.x;
    if (t >= Bc * Gc * Kc) return;
    int g = (t / Kc) % Gc; int b = t / (Kc * Gc);
    int pi = nidx[t];
    const float* p = pos + ((size_t)b * Nn + pi) * 3;
    const float* c = cent + ((size_t)b * Gc + g) * 3;
    float* o = rel + (size_t)t * 3;
    o[0] = p[0]-c[0]; o[1] = p[1]-c[1]; o[2] = p[2]-c[2];
}

__global__ void maxk_kernel(const float* __restrict__ in, float* __restrict__ out, int BG, int C) {
    int t = blockIdx.x * 256 + threadIdx.x;
    if (t >= BG * C) return;
    int c = t % C; int bg = t / C;
    const float* p = in + (size_t)bg * Kc * C + c;
    float m = -INFINITY;
    for (int k = 0; k < Kc; k++) m = fmaxf(m, p[(size_t)k * C]);
    out[t] = m;
}

__global__ void concat_gf_kernel(const float* __restrict__ g, const float* __restrict__ f,
                                 float* __restrict__ cat, int BG) {
    size_t t = (size_t)blockIdx.x * 256 + threadIdx.x;
    size_t total = (size_t)BG * Kc * 512;
    if (t >= total) return;
    int c = (int)(t % 512); size_t bgk = t / 512; size_t bg = bgk / Kc;
    cat[t] = (c < 256) ? g[bg * 256 + c] : f[bgk * 256 + (c - 256)];
}

// -------------------- gather / masks --------------------
__global__ void gather_rows_kernel(const float* __restrict__ in, const int* __restrict__ idx,
                                   float* __restrict__ out, int Ni, int C, int Sin) {
    size_t t = (size_t)blockIdx.x * 256 + threadIdx.x;
    size_t total = (size_t)Bc * Ni * C;
    if (t >= total) return;
    int c = (int)(t % C); size_t bi = t / C; int i = (int)(bi % Ni); int b = (int)(bi / Ni);
    int r = idx[(size_t)b * Ni + i];
    out[t] = in[((size_t)b * Sin + r) * C + c];
}

__global__ void scatter_mask_kernel(const int* __restrict__ nidx, unsigned char* __restrict__ mask,
                                    int Q, int S) {
    int t = blockIdx.x * 256 + threadIdx.x;
    if (t >= Bc * Q * Kc) return;
    int q = (t / Kc) % Q; int b = t / (Kc * Q);
    mask[((size_t)b * Q + q) * S + nidx[t]] = 1;
}

// -------------------- positional encoding (dst = base + pe) --------------------
__global__ void pe_kernel(float* __restrict__ dst, const float* __restrict__ base,
                          const float* __restrict__ xyz, size_t total) {
    size_t t = (size_t)blockIdx.x * 256 + threadIdx.x;
    if (t >= total) return;
    int d = (int)(t % Dd); size_t bs = t / Dd;
    int c = d >> 7;
    int i = d & 127;
    int j = i >> 1;
    float inv = expf(-0.1439115683121279f * (float)j);  // 10000^(-j/64)
    float val = xyz[bs * 3 + c] * inv;
    float pe = (i & 1) ? cosf(val) : sinf(val);
    dst[t] = (base ? base[t] : 0.f) + pe;
}

// -------------------- LayerNorm (no affine), row=384 --------------------
__global__ __launch_bounds__(256) void ln_kernel(const float* __restrict__ X, float* __restrict__ Y, int R) {
    int lane = threadIdx.x & 63;
    int row = blockIdx.x * 4 + (threadIdx.x >> 6);
    if (row >= R) return;
    const float* x = X + (size_t)row * Dd;
    float v[6]; float s = 0.f;
#pragma unroll
    for (int j = 0; j < 6; j++) { v[j] = x[lane + 64*j]; s += v[j]; }
#pragma unroll
    for (int o = 32; o > 0; o >>= 1) s += __shfl_xor(s, o, 64);
    float m = s * (1.f / Dd);
    float s2 = 0.f;
#pragma unroll
    for (int j = 0; j < 6; j++) { float d = v[j] - m; s2 += d * d; }
#pragma unroll
    for (int o = 32; o > 0; o >>= 1) s2 += __shfl_xor(s2, o, 64);
    float inv = rsqrtf(s2 * (1.f / Dd) + 1e-5f);
    float* y = Y + (size_t)row * Dd;
#pragma unroll
    for (int j = 0; j < 6; j++) y[lane + 64*j] = (v[j] - m) * inv;
}

// -------------------- MFMA bf16 GEMM (fp32 A & out, fused bias/relu/residual) --------------------
// 64x64 tile, 256 thr = 4 waves; wave w -> 16-col strip; 4 row-tiles of 16x16x32 MFMA.
// A staged [64][40] bf16 row-major; W staged transposed Bt[n][k] [64][40].
// Layouts (m89/m91/m120-verified): A-frag A[m=lane&15][k=quad*8+j]; B-frag B[k=quad*8+j][n=lane&15];
// C/D: col=lane&15, row=quad*4+reg.
__global__ __launch_bounds__(256) void gemm_kernel(const float* __restrict__ A, const void* __restrict__ Wb,
                                                   size_t wOff, const void* __restrict__ Bb, size_t bOff,
                                                   const float* __restrict__ res, float* __restrict__ C,
                                                   int M, int Ncols, int Kk, int relu,
                                                   const int* __restrict__ flag) {
    __shared__ __bf16 As[64][40];
    __shared__ __bf16 Bs[64][40];
    const int isbf = flag[0];
    const int tid = threadIdx.x;
    const int row0 = blockIdx.y * 64, col0 = blockIdx.x * 64;
    const int w = tid >> 6, lane = tid & 63, m = lane & 15, q = lane >> 4;
    const int arow = tid >> 2, akk = (tid & 3) * 8;   // A: 64 rows x 32 k, 8 k per thread
    const int bk = tid >> 3, bn0 = (tid & 7) * 8;     // W: 32 k x 64 n, 8 n per thread
    const int agm = row0 + arow;
    const bool arowok = (agm < M);
    const float* ap = A + (size_t)agm * Kk;

    f4v acc[4];
#pragma unroll
    for (int r = 0; r < 4; r++) acc[r] = (f4v){0.f, 0.f, 0.f, 0.f};

    for (int k0 = 0; k0 < Kk; k0 += 32) {
        // stage A (fp32 -> bf16)
        {
            union { __bf16 h[8]; uint4 u; } tmp;
#pragma unroll
            for (int i = 0; i < 8; i++) {
                int gk = k0 + akk + i;
                tmp.h[i] = (arowok && gk < Kk) ? f2b(ap[gk]) : f2b(0.f);
            }
            *reinterpret_cast<uint4*>(&As[arow][akk]) = tmp.u;
        }
        // stage W transposed
        {
            int gk = k0 + bk;
            bool kok = (gk < Kk);
            size_t base = wOff + (size_t)gk * Ncols + col0 + bn0;
#pragma unroll
            for (int i = 0; i < 8; i++) {
                int gn = col0 + bn0 + i;
                float v = (kok && gn < Ncols) ? ldf(Wb, base + i, isbf) : 0.f;
                Bs[bn0 + i][bk] = f2b(v);
            }
        }
        __syncthreads();
        bf8v bfrag = *reinterpret_cast<bf8v*>(&Bs[w * 16 + m][q * 8]);
#pragma unroll
        for (int r = 0; r < 4; r++) {
            bf8v afrag = *reinterpret_cast<bf8v*>(&As[r * 16 + m][q * 8]);
            acc[r] = __builtin_amdgcn_mfma_f32_16x16x32_bf16(afrag, bfrag, acc[r], 0, 0, 0);
        }
        __syncthreads();
    }
    const int gn = col0 + w * 16 + m;
    if (gn < Ncols) {
        float bv = Bb ? ldf(Bb, bOff + gn, isbf) : 0.f;
#pragma unroll
        for (int r = 0; r < 4; r++) {
#pragma unroll
            for (int j = 0; j < 4; j++) {
                int gm = row0 + r * 16 + q * 4 + j;
                if (gm < M) {
                    float v = acc[r][j] + bv;
                    if (relu) v = fmaxf(v, 0.f);
                    if (res) v += res[(size_t)gm * Ncols + gn];
                    C[(size_t)gm * Ncols + gn] = v;
                }
            }
        }
    }
}

// -------------------- fused attention: one wave per (bq,h,qi) --------------------
__global__ __launch_bounds__(64) void attn_kernel(const float* __restrict__ Q, const float* __restrict__ Kb,
                                                  const float* __restrict__ Vb,
                                                  const unsigned char* __restrict__ mask,
                                                  float* __restrict__ O, int Sq, int Sk, int b0) {
    int qi = blockIdx.x, h = blockIdx.y, bq = blockIdx.z;
    int bk = bq + b0;
    int lane = threadIdx.x;
    __shared__ float qv[DHh];
    __shared__ float pv[128];
    const size_t qrow = (size_t)bq * Sq + qi;
    if (lane < DHh) qv[lane] = Q[qrow * Dd + h * DHh + lane];
    __syncthreads();
    const float scale = 0.14433756729740643f;  // 1/sqrt(48)
    float lv[2] = {-INFINITY, -INFINITY};
#pragma unroll
    for (int c = 0; c < 2; c++) {
        int s = lane + 64 * c;
        if (s < Sk) {
            const float* kr = Kb + ((size_t)bk * Sk + s) * Dd + h * DHh;
            float d = 0.f;
#pragma unroll
            for (int t = 0; t < DHh; t++) d += qv[t] * kr[t];
            d *= scale;
            if (mask && !mask[qrow * Sk + s]) d = -1e9f;
            lv[c] = d;
        }
    }
    float mx = fmaxf(lv[0], lv[1]);
    for (int o = 32; o > 0; o >>= 1) mx = fmaxf(mx, __shfl_xor(mx, o, 64));
    float sum = 0.f;
#pragma unroll
    for (int c = 0; c < 2; c++) {
        int s = lane + 64 * c;
        if (s < Sk) { float e = expf(lv[c] - mx); pv[s] = e; sum += e; }
    }
    for (int o = 32; o > 0; o >>= 1) sum += __shfl_xor(sum, o, 64);
    float inv = 1.f / sum;
    __syncthreads();
    if (lane < DHh) {
        float acc = 0.f;
        const float* vb = Vb + (size_t)bk * Sk * Dd + h * DHh + lane;
        for (int s = 0; s < Sk; s++) acc += pv[s] * vb[(size_t)s * Dd];
        O[qrow * Dd + h * DHh + lane] = acc * inv;
    }
}

// -------------------- decoder q init --------------------
__global__ void dec_init_kernel(const float* __restrict__ mtok, const float* __restrict__ vout,
                                const float* __restrict__ cpe, const int* __restrict__ mski,
                                const int* __restrict__ visi, float* __restrict__ x) {
    size_t t = (size_t)blockIdx.x * 256 + threadIdx.x;
    size_t total = (size_t)Bc * Gc * Dd;
    if (t >= total) return;
    int d = (int)(t % Dd); size_t bi = t / Dd; int i = (int)(bi % Gc); int b = (int)(bi / Gc);
    float base; int ci;
    if (i < Mc) { base = mtok[d]; ci = mski[b * Mc + i]; }
    else        { base = vout[((size_t)b * Vc + (i - Mc)) * Dd + d]; ci = visi[b * Vc + (i - Mc)]; }
    x[t] = base + cpe[((size_t)b * Gc + ci) * Dd + d];
}

// -------------------- smooth-L1 partial reduce --------------------
__global__ __launch_bounds__(256) void sl1_kernel(const float* __restrict__ tgt, const float* __restrict__ dec,
                                                  float* __restrict__ acc, int slot) {
    __shared__ float sh[256];
    size_t t = (size_t)blockIdx.x * 256 + threadIdx.x;
    const size_t total = (size_t)Bc * Mc * Dd;
    float v = 0.f;
    if (t < total) {
        int d = (int)(t % Dd); size_t rem = t / Dd; int i = (int)(rem % Mc); int b = (int)(rem / Mc);
        float p = dec[((size_t)b * Gc + i) * Dd + d];
        float a = fabsf(p - tgt[t]);
        v = (a < 2.f) ? 0.25f * a * a : (a - 1.f);
    }
    sh[threadIdx.x] = v;
    __syncthreads();
    for (int s = 128; s > 0; s >>= 1) {
        if (threadIdx.x < s) sh[threadIdx.x] += sh[threadIdx.x + s];
        __syncthreads();
    }
    if (threadIdx.x == 0) atomicAdd(&acc[slot], sh[0]);
}

__global__ void mae_finalize_kernel(const float* __restrict__ acc, float* __restrict__ out) {
    const float inv = 1.f / (float)(Bc * Mc * Dd);
    *out = 0.5f * (acc[0] * inv) + 0.5f * (acc[1] * inv);
}

// ==================== host orchestration ====================
extern "C" void kernel_launch(void* const* d_in, const int* in_sizes, int n_in,
                              void* d_out, int out_size, void* d_ws, size_t ws_size,
                              hipStream_t stream) {
    (void)in_sizes; (void)n_in; (void)out_size;
    const void* pos_src = d_in[0];
    const void* pos_tgt = d_in[1];
    const int* vis_s = (const int*)d_in[2];
    const int* msk_s = (const int*)d_in[3];
    const int* vis_t = (const int*)d_in[4];
    const int* msk_t = (const int*)d_in[5];
    const void *tw1 = d_in[6], *tb1 = d_in[7], *tw2 = d_in[8], *tb2 = d_in[9];
    const void *tw3 = d_in[10], *tb3 = d_in[11], *tw4 = d_in[12], *tb4 = d_in[13];
    const void *mtok = d_in[14];
    const void *cxw = d_in[15], *cff1 = d_in[16], *cff2 = d_in[17];
    const void *esa = d_in[18], *eca = d_in[19], *eff1 = d_in[20], *eff2 = d_in[21];
    const void *dca = d_in[22], *dff1 = d_in[23], *dff2 = d_in[24];
    const void *uw1 = d_in[25], *ub1 = d_in[26], *uw2 = d_in[27], *ub2 = d_in[28];
    float* out = (float*)d_out;                      // fp32 output
    char* ws = (char*)d_ws;

    const size_t DD = (size_t)Dd * Dd;
    const size_t DF = (size_t)Dd * FFf;

    // ---- persistent workspace layout ----
    size_t o = 0;
    auto alloc = [&](size_t bytes) -> size_t { size_t r = o; o += (bytes + 255) & ~(size_t)255; return r; };
    const size_t flagO = alloc(256);
    const size_t mtokO = alloc(Dd * 4);
    const size_t posf_s = alloc((size_t)Bc*Nn*3*4), posf_t = alloc((size_t)Bc*Nn*3*4);
    const size_t cent_s = alloc((size_t)Bc*Gc*3*4), cent_t = alloc((size_t)Bc*Gc*3*4);
    const size_t cpe_s = alloc((size_t)Bc*Gc*Dd*4), cpe_t = alloc((size_t)Bc*Gc*Dd*4);
    const size_t tok_s = alloc((size_t)Bc*Gc*Dd*4), tok_t = alloc((size_t)Bc*Gc*Dd*4);
    const size_t vtok_s = alloc((size_t)Bc*Vc*Dd*4), vtok_t = alloc((size_t)Bc*Vc*Dd*4);
    const size_t lnS = alloc((size_t)Bc*Gc*Dd*4), lnT = alloc((size_t)Bc*Gc*Dd*4);
    const size_t qb = alloc((size_t)Bc*Gc*Dd*4), kb = alloc((size_t)Bc*Gc*Dd*4);
    const size_t vb = alloc((size_t)Bc*Gc*Dd*4), cx = alloc((size_t)Bc*Gc*Dd*4);
    const size_t decx_s = alloc((size_t)Bc*Gc*Dd*4), decx_t = alloc((size_t)Bc*Gc*Dd*4);
    const size_t memb = alloc((size_t)Bc*Gc*Dd*4), lnm = alloc((size_t)Bc*Gc*Dd*4);
    const size_t kl0 = alloc((size_t)Bc*Gc*Dd*4), vl0 = alloc((size_t)Bc*Gc*Dd*4);
    const size_t kl1 = alloc((size_t)Bc*Gc*Dd*4), vl1 = alloc((size_t)Bc*Gc*Dd*4);
    const size_t relb = alloc((size_t)Bc*Gc*Kc*3*4);
    const size_t tbs = alloc((size_t)Bc*Mc*Dd*4), tbt = alloc((size_t)Bc*Mc*Dd*4);
    const size_t mfull_s = alloc((size_t)Bc*Gc*Gc), mfull_t = alloc((size_t)Bc*Gc*Gc);
    const size_t mvis_s = alloc((size_t)Bc*Vc*Vc), mvis_t = alloc((size_t)Bc*Vc*Vc);
    const size_t nidxb = alloc((size_t)Bc*Gc*Kc*4);
    const size_t idx3b = alloc((size_t)Bc*Nn*3*4), w3b = alloc((size_t)Bc*Nn*3*4);
    const size_t vis3_s = alloc((size_t)Bc*Vc*3*4), vis3_t = alloc((size_t)Bc*Vc*3*4);
    const size_t accb = alloc(64);

    // ---- chunk size selection based on ws_size ----
    int CH = 256;
    {
        const int cands[5] = {4096, 2048, 1024, 512, 256};
        for (int ci = 0; ci < 5; ci++) {
            size_t need = o + (size_t)cands[ci] * 3715 * 4 + 8 * 256;
            if (need <= ws_size) { CH = cands[ci]; break; }
        }
    }
    const size_t AcbO = alloc((size_t)CH*387*4);
    const size_t XcO  = alloc((size_t)CH*384*4);
    const size_t LcO  = alloc((size_t)CH*384*4);
    const size_t T1O  = alloc((size_t)CH*512*4);
    const size_t T2O  = alloc((size_t)CH*512*4);
    const size_t HhO  = alloc((size_t)CH*FFf*4);

    auto F = [&](size_t off) -> float* { return (float*)(ws + off); };
    auto I = [&](size_t off) -> int* { return (int*)(ws + off); };
    auto U = [&](size_t off) -> unsigned char* { return (unsigned char*)(ws + off); };
    auto ew = [](size_t n) -> dim3 { return dim3((unsigned)((n + 255) / 256)); };
    const int* flag = I(flagO);

    auto gemm = [&](const float* A, const void* W, size_t wOff, const void* bias, size_t bOff,
                    const float* res, float* C, int M, int Ncol, int Kk, int relu) {
        dim3 g((Ncol + 63) / 64, (M + 63) / 64);
        gemm_kernel<<<g, 256, 0, stream>>>(A, W, wOff, bias, bOff, res, C, M, Ncol, Kk, relu, flag);
    };
    auto ln = [&](const float* X, float* Y, int R) {
        ln_kernel<<<dim3((R + 3) / 4), 256, 0, stream>>>(X, Y, R);
    };
    auto attn = [&](const float* Qp, const float* Kp, const float* Vp, const unsigned char* mask,
                    float* Op, int Sq, int Sk, int nb, int b0) {
        attn_kernel<<<dim3(Sq, NHh, nb), 64, 0, stream>>>(Qp, Kp, Vp, mask, Op, Sq, Sk, b0);
    };
    float *qbuf = F(qb), *kbuf = F(kb), *vbuf = F(vb), *ctx = F(cx);
    auto attn_block = [&](float* x, const float* qln, const float* kln, const void* w, size_t wo,
                          const unsigned char* mask, int S) {
        gemm(qln, w, wo,        nullptr, 0, nullptr, qbuf, Bc*S, Dd, Dd, 0);
        gemm(kln, w, wo + DD,   nullptr, 0, nullptr, kbuf, Bc*S, Dd, Dd, 0);
        gemm(kln, w, wo + 2*DD, nullptr, 0, nullptr, vbuf, Bc*S, Dd, Dd, 0);
        attn(qbuf, kbuf, vbuf, mask, ctx, S, S, Bc, 0);
        gemm(ctx, w, wo + 3*DD, nullptr, 0, x, x, Bc*S, Dd, Dd, 0);
    };
    auto ffn = [&](float* x, const void* w1, size_t w1o, const void* w2, size_t w2o, int R) {
        ln(x, F(lnS), R);
        for (int r0 = 0; r0 < R; r0 += CH) {
            int rc = (R - r0 < CH) ? (R - r0) : CH;
            gemm(F(lnS) + (size_t)r0*Dd, w1, w1o, nullptr, 0, nullptr, F(HhO), rc, FFf, Dd, 1);
            gemm(F(HhO), w2, w2o, nullptr, 0, x + (size_t)r0*Dd, x + (size_t)r0*Dd, rc, Dd, FFf, 0);
        }
    };
    auto cross_enc = [&](float* xs, float* xt, const unsigned char* ms, const unsigned char* mt, int S) {
        ln(xs, F(lnS), Bc*S); attn_block(xs, F(lnS), F(lnS), cxw, 0, ms, S);
        ln(xt, F(lnT), Bc*S); attn_block(xt, F(lnT), F(lnT), cxw, 0, mt, S);
        ln(xs, F(lnS), Bc*S); ln(xt, F(lnT), Bc*S);
        attn_block(xs, F(lnS), F(lnT), cxw, 4*DD, nullptr, S);
        attn_block(xt, F(lnT), F(lnS), cxw, 4*DD, nullptr, S);
        ffn(xs, cff1, 0, cff2, 0, Bc*S);
        ffn(xt, cff1, 0, cff2, 0, Bc*S);
    };
    auto decoder4 = [&](float* x, const float* memin, const float* cpem) {
        add_kernel<<<ew((size_t)Bc*Gc*Dd), 256, 0, stream>>>(memin, cpem, F(memb), (size_t)Bc*Gc*Dd);
        ln(F(memb), F(lnm), Bc*Gc);
        for (int l = 0; l < 4; l++) {
            ln(x, F(lnT), Bc*Gc);
            attn_block(x, F(lnT), F(lnT), esa, (size_t)l*4*DD, nullptr, Gc);
            ln(x, F(lnT), Bc*Gc);
            attn_block(x, F(lnT), F(lnm), eca, (size_t)l*4*DD, nullptr, Gc);
            ffn(x, eff1, (size_t)l*DF, eff2, (size_t)l*DF, Bc*Gc);
        }
    };
    auto tokenize = [&](const float* posf, float* cent, float* tok) {
        fps_kernel<<<dim3(Bc), 256, 0, stream>>>(posf, cent);
        knn16_kernel<<<dim3(Bc*Gc), 64, 0, stream>>>(cent, posf, I(nidxb), Gc, Nn);
        rel_kernel<<<ew((size_t)Bc*Gc*Kc), 256, 0, stream>>>(posf, cent, I(nidxb), F(relb));
        const int GC = CH / Kc;             // groups per chunk
        float* Hh0 = F(HhO);                      // cat (CH x 512)
        float* Hh1 = F(HhO) + (size_t)CH * 512;   // hb  (CH x 512)
        for (int g0 = 0; g0 < Bc*Gc; g0 += GC) {
            const int RC = GC * Kc;
            gemm(F(relb) + (size_t)g0*Kc*3, tw1, 0, tb1, 0, nullptr, F(T1O), RC, 128, 3, 1);
            gemm(F(T1O), tw2, 0, tb2, 0, nullptr, F(T2O), RC, 256, 128, 0);
            maxk_kernel<<<ew((size_t)GC*256), 256, 0, stream>>>(F(T2O), F(XcO), GC, 256);
            concat_gf_kernel<<<ew((size_t)RC*512), 256, 0, stream>>>(F(XcO), F(T2O), Hh0, GC);
            gemm(Hh0, tw3, 0, tb3, 0, nullptr, Hh1, RC, 512, 512, 1);
            gemm(Hh1, tw4, 0, tb4, 0, nullptr, F(XcO), RC, Dd, 512, 0);
            maxk_kernel<<<ew((size_t)GC*Dd), 256, 0, stream>>>(F(XcO), tok + (size_t)g0*Dd, GC, Dd);
        }
    };
    auto dense_side = [&](const float* posf, const float* cent, const float* feats,
                          const float* cpe_side, float* outp) {
        knn3_kernel<<<dim3(Bc*Nn), 64, 0, stream>>>(posf, cent, I(idx3b), F(w3b));
        add_kernel<<<ew((size_t)Bc*Gc*Dd), 256, 0, stream>>>(feats, cpe_side, F(memb), (size_t)Bc*Gc*Dd);
        ln(F(memb), F(lnm), Bc*Gc);
        gemm(F(lnm), dca, 0*4*DD + DD,   nullptr, 0, nullptr, F(kl0), Bc*Gc, Dd, Dd, 0);
        gemm(F(lnm), dca, 0*4*DD + 2*DD, nullptr, 0, nullptr, F(vl0), Bc*Gc, Dd, Dd, 0);
        gemm(F(lnm), dca, 1*4*DD + DD,   nullptr, 0, nullptr, F(kl1), Bc*Gc, Dd, Dd, 0);
        gemm(F(lnm), dca, 1*4*DD + 2*DD, nullptr, 0, nullptr, F(vl1), Bc*Gc, Dd, Dd, 0);
        const size_t kvo[2][2] = {{kl0, vl0}, {kl1, vl1}};
        for (int b = 0; b < Bc; b++) {
            for (int c0 = 0; c0 < Nn; c0 += CH) {
                const int r0 = b * Nn + c0;
                interp_kernel<<<ew((size_t)CH*387), 256, 0, stream>>>(feats, posf, I(idx3b), F(w3b), F(AcbO), r0, CH);
                gemm(F(AcbO), uw1, 0, ub1, 0, nullptr, F(XcO), CH, Dd, 387, 1);
                gemm(F(XcO), uw2, 0, ub2, 0, nullptr, F(LcO), CH, Dd, Dd, 1);
                pe_kernel<<<ew((size_t)CH*Dd), 256, 0, stream>>>(F(XcO), F(LcO), posf + (size_t)r0*3, (size_t)CH*Dd);
                for (int l = 0; l < 2; l++) {
                    ln(F(XcO), F(LcO), CH);
                    gemm(F(LcO), dca, (size_t)l*4*DD, nullptr, 0, nullptr, F(T1O), CH, Dd, Dd, 0);
                    attn(F(T1O), F(kvo[l][0]), F(kvo[l][1]), nullptr, F(T2O), CH, Gc, 1, b);
                    gemm(F(T2O), dca, (size_t)l*4*DD + 3*DD, nullptr, 0, F(XcO), F(XcO), CH, Dd, Dd, 0);
                    ln(F(XcO), F(LcO), CH);
                    gemm(F(LcO), dff1, (size_t)l*DF, nullptr, 0, nullptr, F(HhO), CH, FFf, Dd, 1);
                    gemm(F(HhO), dff2, (size_t)l*DF, nullptr, 0, F(XcO), F(XcO), CH, Dd, FFf, 0);
                }
                copyout_kernel<<<ew((size_t)CH*Dd), 256, 0, stream>>>(F(XcO), outp + (size_t)r0*Dd, (size_t)CH*Dd);
            }
        }
    };

    // ---- pipeline ----
    detect_kernel<<<dim3(1), 256, 0, stream>>>((const unsigned int*)pos_src, I(flagO));
    cvtf_kernel<<<ew((size_t)Bc*Nn*3), 256, 0, stream>>>(pos_src, F(posf_s), (size_t)Bc*Nn*3, flag);
    cvtf_kernel<<<ew((size_t)Bc*Nn*3), 256, 0, stream>>>(pos_tgt, F(posf_t), (size_t)Bc*Nn*3, flag);
    cvtf_kernel<<<dim3(2), 256, 0, stream>>>(mtok, F(mtokO), (size_t)Dd, flag);

    tokenize(F(posf_s), F(cent_s), F(tok_s));
    tokenize(F(posf_t), F(cent_t), F(tok_t));

    pe_kernel<<<ew((size_t)Bc*Gc*Dd), 256, 0, stream>>>(F(cpe_s), nullptr, F(cent_s), (size_t)Bc*Gc*Dd);
    pe_kernel<<<ew((size_t)Bc*Gc*Dd), 256, 0, stream>>>(F(cpe_t), nullptr, F(cent_t), (size_t)Bc*Gc*Dd);

    gather_rows_kernel<<<ew((size_t)Bc*Vc*Dd), 256, 0, stream>>>(F(tok_s), vis_s, F(vtok_s), Vc, Dd, Gc);
    gather_rows_kernel<<<ew((size_t)Bc*Vc*Dd), 256, 0, stream>>>(F(tok_t), vis_t, F(vtok_t), Vc, Dd, Gc);
    gather_rows_kernel<<<ew((size_t)Bc*Vc*3), 256, 0, stream>>>(F(cent_s), vis_s, F(vis3_s), Vc, 3, Gc);
    gather_rows_kernel<<<ew((size_t)Bc*Vc*3), 256, 0, stream>>>(F(cent_t), vis_t, F(vis3_t), Vc, 3, Gc);

    zero_kernel<<<ew((size_t)Bc*Gc*Gc), 256, 0, stream>>>(U(mfull_s), (size_t)Bc*Gc*Gc);
    knn16_kernel<<<dim3(Bc*Gc), 64, 0, stream>>>(F(cent_s), F(cent_s), I(nidxb), Gc, Gc);
    scatter_mask_kernel<<<ew((size_t)Bc*Gc*Kc), 256, 0, stream>>>(I(nidxb), U(mfull_s), Gc, Gc);
    zero_kernel<<<ew((size_t)Bc*Gc*Gc), 256, 0, stream>>>(U(mfull_t), (size_t)Bc*Gc*Gc);
    knn16_kernel<<<dim3(Bc*Gc), 64, 0, stream>>>(F(cent_t), F(cent_t), I(nidxb), Gc, Gc);
    scatter_mask_kernel<<<ew((size_t)Bc*Gc*Kc), 256, 0, stream>>>(I(nidxb), U(mfull_t), Gc, Gc);
    zero_kernel<<<ew((size_t)Bc*Vc*Vc), 256, 0, stream>>>(U(mvis_s), (size_t)Bc*Vc*Vc);
    knn16_kernel<<<dim3(Bc*Vc), 64, 0, stream>>>(F(vis3_s), F(vis3_s), I(nidxb), Vc, Vc);
    scatter_mask_kernel<<<ew((size_t)Bc*Vc*Kc), 256, 0, stream>>>(I(nidxb), U(mvis_s), Vc, Vc);
    zero_kernel<<<ew((size_t)Bc*Vc*Vc), 256, 0, stream>>>(U(mvis_t), (size_t)Bc*Vc*Vc);
    knn16_kernel<<<dim3(Bc*Vc), 64, 0, stream>>>(F(vis3_t), F(vis3_t), I(nidxb), Vc, Vc);
    scatter_mask_kernel<<<ew((size_t)Bc*Vc*Kc), 256, 0, stream>>>(I(nidxb), U(mvis_t), Vc, Vc);

    cross_enc(F(vtok_s), F(vtok_t), U(mvis_s), U(mvis_t), Vc);
    cross_enc(F(tok_s), F(tok_t), U(mfull_s), U(mfull_t), Gc);

    dec_init_kernel<<<ew((size_t)Bc*Gc*Dd), 256, 0, stream>>>(F(mtokO), F(vtok_s), F(cpe_s), msk_s, vis_s, F(decx_s));
    dec_init_kernel<<<ew((size_t)Bc*Gc*Dd), 256, 0, stream>>>(F(mtokO), F(vtok_t), F(cpe_t), msk_t, vis_t, F(decx_t));
    decoder4(F(decx_s), F(tok_t), F(cpe_t));
    decoder4(F(decx_t), F(tok_s), F(cpe_s));

    zero_kernel<<<dim3(1), 256, 0, stream>>>(U(accb), 64);
    gather_rows_kernel<<<ew((size_t)Bc*Mc*Dd), 256, 0, stream>>>(F(tok_s), msk_s, F(tbs), Mc, Dd, Gc);
    gather_rows_kernel<<<ew((size_t)Bc*Mc*Dd), 256, 0, stream>>>(F(tok_t), msk_t, F(tbt), Mc, Dd, Gc);
    sl1_kernel<<<ew((size_t)Bc*Mc*Dd), 256, 0, stream>>>(F(tbs), F(decx_s), F(accb), 0);
    sl1_kernel<<<ew((size_t)Bc*Mc*Dd), 256, 0, stream>>>(F(tbt), F(decx_t), F(accb), 1);

    dense_side(F(posf_s), F(cent_s), F(tok_s), F(cpe_s), out);
    dense_side(F(posf_t), F(cent_t), F(tok_t), F(cpe_t), out + (size_t)Bc*Nn*Dd);

    mae_finalize_kernel<<<dim3(1), 1, 0, stream>>>(F(accb), out + (size_t)2*Bc*Nn*Dd);
}